// Round 5
// baseline (203.623 us; speedup 1.0000x reference)
//
#include <hip/hip_runtime.h>
#include <math.h>

#define NB 512
#define NN 64
#define TL 657
#define LV1 328
#define LV2 164
#define LV3 82
#define LV4 41
#define HID 82
#define BAND 219   // 657/3
#define ST 66      // padded LDS stride for 64x64 matrices (bank-spread)

// workspace byte offsets (aliased by liveness; max ~9.8 MB)
#define WS_M      0          // 2*4096 f32
#define WS_ACC    32768      // 512 doubles
#define WS_SMEAN  36864
#define WS_SMAX   167936
#define WS_FC2T   299008     // 82*657 f32 -> ends 514504 (pad 514560)
#define WS_H      514560     // 512*82 f32 -> ends 682496
#define WS_CSUM   682496     // 512*657 f32 -> ends 2028032
#define WS_CMAX   2028032    // -> ends 3373568
#define WS_CATT   3373568    // -> ends 4719104
#define WS_Y1     682496     // 512*64*32 f32 (aliases csum/cmax/catt; dead by gcn1) ends 4876800
#define WS_DELTA  4876800    // 512*64*41 f32 -> ends 10250752
#define WS_Y2     4876800    // aliases delta (dead by gcn2)
#define WS_OUT1   5925376    // 512*32 f32

// accumulator (double) indices
#define ACC_Y1 0
#define ACC_Y2 64
#define ACC_O1 80

__device__ __forceinline__ float sigmoidf_(float v){ return 1.0f/(1.0f+expf(-v)); }

__device__ __forceinline__ void wav_level(float* __restrict__ dst, const float* __restrict__ src,
                                          int outL, int inL, int lane){
  const float DLO[8] = {0.23037781330885523f, 0.7148465705525415f, 0.6308807679295904f,
                        -0.02798376941698385f, -0.18703481171888114f, 0.030841381835986965f,
                        0.032883011666982945f, -0.010597401784997278f};
  for (int k=lane; k<outL; k+=64){
    int i0 = 2*k - 3;
    float a = 0.f;
    #pragma unroll
    for (int j=0;j<8;j++){
      int idx = i0 + j;
      idx = (idx < 0) ? idx + inL : ((idx >= inL) ? idx - inL : idx);
      a += src[idx]*DLO[j];
    }
    dst[k] = a;
  }
}

// 64x64 matmul in padded LDS (stride ST): D = A*B. 4 waves, 16 rows/wave.
// A-row reads are wave-uniform float2 broadcasts; 4 accumulators for ILP.
__device__ __forceinline__ void mm64p(float* __restrict__ D, const float* __restrict__ A,
                                      const float* __restrict__ Bm){
  int tid = threadIdx.x;
  int wv = tid >> 6, lane = tid & 63;
  float bb[64];
  #pragma unroll
  for (int k=0;k<64;k++) bb[k] = Bm[k*ST + lane];
  int i0 = wv*16;
  for (int i=0;i<16;i++){
    const float2* ar = (const float2*)&A[(i0+i)*ST];
    float a0=0.f,a1=0.f,a2=0.f,a3=0.f;
    #pragma unroll
    for (int k2=0;k2<32;k2+=2){
      float2 v0 = ar[k2], v1 = ar[k2+1];
      a0 += v0.x*bb[2*k2  ]; a1 += v0.y*bb[2*k2+1];
      a2 += v1.x*bb[2*k2+2]; a3 += v1.y*bb[2*k2+3];
    }
    D[(i0+i)*ST + lane] = (a0+a1)+(a2+a3);
  }
}

// ---------------- graph prep (blocks 0,1) + fc2 transpose (blocks 2..9) ----------------
__global__ __launch_bounds__(256) void k_graph(
    const float* __restrict__ lgw, const float* __restrict__ gmask,
    const float* __restrict__ tril, const int* __restrict__ edges,
    const float* __restrict__ fc2,
    float* __restrict__ Mout, float* __restrict__ fc2T,
    double* __restrict__ acc)
{
  int tid = threadIdx.x;
  if (blockIdx.x >= 2){
    int gi = blockIdx.x - 2;   // 0..7
    for (int i = gi*256 + tid; i < HID*TL; i += 8*256){
      int c2 = i / HID, u = i - c2*HID;
      fc2T[u*TL + c2] = fc2[i];
    }
    return;
  }
  __shared__ float Wbuf[NN*ST];   // edge weights (4096 used), later reused as Q = (A^2)^2
  __shared__ float Amat[NN*ST];   // normalized adjacency A (padded stride)
  __shared__ float P1[NN*ST];     // A^2
  __shared__ float deg[64], hs[64], dinv[64], wself[64];
  int g = blockIdx.x;
  if (g==0){ for (int i=tid;i<512;i+=256) acc[i]=0.0; }
  for (int e=tid;e<4096;e+=256){
    float w;
    if (g==0) w = lgw[e];
    else {
      int i=e>>6, j=e&63;
      int aa = (i>j)? i:j, bb = (i>j)? j:i;
      w = tril[aa*(aa+1)/2 + bb] * gmask[e];
    }
    Wbuf[e] = w;
  }
  for (int i=tid;i<NN*ST;i+=256) Amat[i] = 0.f;
  if (tid<64){ deg[tid]=0.f; hs[tid]=0.f; }
  __syncthreads();
  // deg: run-length accumulation over a contiguous 16-edge chunk per thread
  {
    int e0 = tid*16;
    int runr = edges[e0];
    float runv = 0.f;
    #pragma unroll 4
    for (int i=0;i<16;i++){
      int e = e0+i;
      int r = edges[e];
      int c = edges[4096+e];
      float w = Wbuf[e];
      if (r != runr){ atomicAdd(&deg[runr], runv); runr = r; runv = 0.f; }
      runv += fabsf(w);
      if (r == c) hs[r] = 1.f;
    }
    atomicAdd(&deg[runr], runv);
  }
  __syncthreads();
  if (tid<64){
    float w_ = (hs[tid] > 0.f) ? 0.f : 1.f;
    float d = deg[tid] + w_;
    dinv[tid] = (d > 0.f) ? rsqrtf(d) : 0.f;
    wself[tid] = w_;
  }
  __syncthreads();
  // scatter normalized weights: bank (2c+r)%32 -> 4-way max
  for (int e=tid;e<4096;e+=256){
    int r = edges[e], c = edges[4096+e];
    float nm = dinv[r]*Wbuf[e]*dinv[c];
    atomicAdd(&Amat[c*ST+r], nm);
  }
  __syncthreads();
  if (tid<64) Amat[tid*ST+tid] += dinv[tid]*wself[tid]*dinv[tid];
  __syncthreads();
  mm64p(P1, Amat, Amat); __syncthreads();   // A^2
  mm64p(Wbuf, P1, P1);   __syncthreads();   // A^4 (over dead W)
  { // M = A^4 * A -> global (row-major stride 64)
    int wv = tid>>6, lane = tid&63;
    float bb[64];
    #pragma unroll
    for (int k=0;k<64;k++) bb[k] = Amat[k*ST + lane];
    int i0 = wv*16;
    for (int i=0;i<16;i++){
      const float2* ar = (const float2*)&Wbuf[(i0+i)*ST];
      float a0=0.f,a1=0.f,a2=0.f,a3=0.f;
      #pragma unroll
      for (int k2=0;k2<32;k2+=2){
        float2 v0 = ar[k2], v1 = ar[k2+1];
        a0 += v0.x*bb[2*k2  ]; a1 += v0.y*bb[2*k2+1];
        a2 += v1.x*bb[2*k2+2]; a3 += v1.y*bb[2*k2+3];
      }
      Mout[g*4096 + (i0+i)*64 + lane] = (a0+a1)+(a2+a3);
    }
  }
}

// ---------------- channel stats: grid (512, 3), 16-deep load batching ----------------
__global__ __launch_bounds__(256) void k_stats(
    const float* __restrict__ x,
    float* __restrict__ csum, float* __restrict__ cmax)
{
  int tid = threadIdx.x, b = blockIdx.x, band = blockIdx.y;
  if (tid >= BAND) return;
  int col = band*BAND + tid;
  const float* p = x + (size_t)b*NN*TL + col;
  float s = 0.f, m = -INFINITY;
  for (int n=0;n<NN;n+=16){
    float v0 = p[0*TL],  v1 = p[1*TL],  v2 = p[2*TL],  v3 = p[3*TL];
    float v4 = p[4*TL],  v5 = p[5*TL],  v6 = p[6*TL],  v7 = p[7*TL];
    float v8 = p[8*TL],  v9 = p[9*TL],  vA = p[10*TL], vB = p[11*TL];
    float vC = p[12*TL], vD = p[13*TL], vE = p[14*TL], vF = p[15*TL];
    p += 16*TL;
    s += ((v0+v1)+(v2+v3)) + ((v4+v5)+(v6+v7)) + ((v8+v9)+(vA+vB)) + ((vC+vD)+(vE+vF));
    float m01 = fmaxf(fmaxf(v0,v1), fmaxf(v2,v3));
    float m23 = fmaxf(fmaxf(v4,v5), fmaxf(v6,v7));
    float m45 = fmaxf(fmaxf(v8,v9), fmaxf(vA,vB));
    float m67 = fmaxf(fmaxf(vC,vD), fmaxf(vE,vF));
    m = fmaxf(m, fmaxf(fmaxf(m01,m23), fmaxf(m45,m67)));
  }
  csum[(size_t)b*TL + col] = s;
  cmax[(size_t)b*TL + col] = m;
}

// ---------------- MLP layer 1: wave-per-output, stats in registers: grid (512,2) ----------------
__global__ __launch_bounds__(256) void k_mlp1(
    const float* __restrict__ csum, const float* __restrict__ cmax,
    const float* __restrict__ fc1, float* __restrict__ H)
{
  int tid = threadIdx.x, b = blockIdx.x, half = blockIdx.y;
  int wv = tid>>6, lane = tid&63;
  float s[11], m[11];
  #pragma unroll
  for (int i=0;i<11;i++){
    int c = lane + 64*i;
    bool ok = c < TL;
    s[i] = ok ? csum[(size_t)b*TL+c] : 0.f;
    m[i] = ok ? cmax[(size_t)b*TL+c] : 0.f;
  }
  int oend = half*41 + 41; if (oend > HID) oend = HID;
  for (int o = half*41 + wv; o < oend; o += 4){
    const float* fr = fc1 + (size_t)o*TL;
    float a = 0.f, bm = 0.f;
    #pragma unroll
    for (int i=0;i<11;i++){
      int c = lane + 64*i;
      float f = (c<TL) ? fr[c] : 0.f;
      a += f*s[i]; bm += f*m[i];
    }
    #pragma unroll
    for (int off=32;off;off>>=1){
      a  += __shfl_xor(a,off);
      bm += __shfl_xor(bm,off);
    }
    if (lane==0)
      H[(size_t)b*HID + o] = fmaxf(a*(1.0f/64.0f),0.f) + fmaxf(bm,0.f);
  }
}

// ---------------- MLP layer 2 -> catt: 3 columns/thread, coalesced fc2T: grid 512 ----------------
__global__ __launch_bounds__(256) void k_mlp2(
    const float* __restrict__ H, const float* __restrict__ fc2T,
    float* __restrict__ catt)
{
  __shared__ float h[HID];
  int tid = threadIdx.x, b = blockIdx.x;
  if (tid < HID) h[tid] = H[(size_t)b*HID + tid];
  __syncthreads();
  int c0 = tid, c1 = tid+256, c2 = tid+512;
  bool ok2 = c2 < TL;
  float a0=0.f, a1=0.f, a2=0.f;
  #pragma unroll 2
  for (int u=0;u<HID;u++){
    const float* fr = fc2T + (size_t)u*TL;
    float hv = h[u];
    a0 += fr[c0]*hv;
    a1 += fr[c1]*hv;
    if (ok2) a2 += fr[c2]*hv;
  }
  size_t base = (size_t)b*TL;
  catt[base+c0] = sigmoidf_(a0);
  catt[base+c1] = sigmoidf_(a1);
  if (ok2) catt[base+c2] = sigmoidf_(a2);
}

// ---------------- wavelet cascade + spatial stats: grid (512,16), one row per wave ----------------
__global__ __launch_bounds__(256) void k_wav(
    const float* __restrict__ x, const float* __restrict__ catt_g,
    float* __restrict__ delta, float* __restrict__ smean, float* __restrict__ smax)
{
  __shared__ float catt[TL];
  __shared__ float yb[4][TL];
  __shared__ float o1b[4][LV1];
  __shared__ float o2b[4][LV2];
  __shared__ float o3b[4][LV3];
  int tid = threadIdx.x, b = blockIdx.x;
  for (int i=tid;i<TL;i+=256) catt[i] = catt_g[(size_t)b*TL + i];
  __syncthreads();
  int wv = tid>>6, lane = tid&63;
  int n = blockIdx.y*4 + wv;
  float* y  = yb[wv];
  float* p1 = o1b[wv];
  float* p2 = o2b[wv];
  float* p3 = o3b[wv];
  const float DLO[8] = {0.23037781330885523f, 0.7148465705525415f, 0.6308807679295904f,
                        -0.02798376941698385f, -0.18703481171888114f, 0.030841381835986965f,
                        0.032883011666982945f, -0.010597401784997278f};
  const float* row = x + ((size_t)b*NN + n)*TL;
  float ls = 0.f, lm = -INFINITY;
  #pragma unroll
  for (int i=0;i<11;i++){
    int t = lane + 64*i;
    if (t < TL){
      float v = row[t]*catt[t];
      y[t] = v; ls += v; lm = fmaxf(lm,v);
    }
  }
  #pragma unroll
  for (int off=32;off;off>>=1){
    ls += __shfl_xor(ls,off);
    lm = fmaxf(lm, __shfl_xor(lm,off));
  }
  if (lane==0){ smean[b*NN+n] = ls*(1.0f/657.0f); smax[b*NN+n] = lm; }
  wav_level(p1, y,  LV1, TL,  lane);
  wav_level(p2, p1, LV2, LV1, lane);
  wav_level(p3, p2, LV3, LV2, lane);
  if (lane < LV4){
    int i0 = 2*lane - 3;
    float a = 0.f;
    #pragma unroll
    for (int j=0;j<8;j++){
      int idx = i0 + j;
      idx = (idx < 0) ? idx + LV3 : ((idx >= LV3) ? idx - LV3 : idx);
      a += p3[idx]*DLO[j];
    }
    delta[((size_t)b*NN + n)*LV4 + lane] = a;
  }
}

// ---------------- GCN block 1 (+ fused spatial attention scale) ----------------
__global__ __launch_bounds__(256) void k_gcn1(
  const float* __restrict__ delta, const float* __restrict__ Mmat,
  const float* __restrict__ smean, const float* __restrict__ smax,
  const float* __restrict__ saw,
  const float* __restrict__ ldW, const float* __restrict__ ldb,
  const float* __restrict__ dW, const float* __restrict__ db2,
  float* __restrict__ Y1, double* __restrict__ acc)
{
  __shared__ float Dl[NN*LV4];
  __shared__ float Tt[NN*16];
  __shared__ float Mm[4096];
  __shared__ float Wl[16*LV4];
  __shared__ float satt[NN];
  __shared__ double red[256];
  int tid=threadIdx.x, b=blockIdx.x;
  if (tid < NN){
    float a = 0.f;
    #pragma unroll
    for (int kw=0;kw<7;kw++){
      int w = tid + kw - 3;
      if (0<=w && w<NN) a += smean[b*NN+w]*saw[21+kw] + smax[b*NN+w]*saw[70+kw];
    }
    satt[tid] = sigmoidf_(a);
  }
  __syncthreads();
  const float* ds = delta + (size_t)b*NN*LV4;
  for (int i=tid;i<NN*LV4;i+=256) Dl[i] = ds[i]*satt[i/LV4];
  for (int g=0; g<2; g++){
    const float* Ws = g ? dW : ldW;
    const float* bs = g ? db2 : ldb;
    for (int i=tid;i<16*LV4;i+=256) Wl[i]=Ws[i];
    for (int i=tid;i<4096;i+=256) Mm[i]=Mmat[g*4096+i];
    __syncthreads();
    for (int e=tid;e<NN*16;e+=256){
      int n=e>>4, o=e&15;
      const float* dr=&Dl[n*LV4];
      const float* wr=&Wl[o*LV4];
      float a=0.f;
      #pragma unroll 8
      for (int c=0;c<LV4;c++) a += dr[c]*wr[c];
      Tt[e]=a;
    }
    __syncthreads();
    float bias = bs[tid&15];
    float ps=0.f, pq=0.f;
    for (int m=0;m<4;m++){
      int e=tid+256*m;
      int n=e>>4, o=e&15;
      float a=bias;
      #pragma unroll 8
      for (int k=0;k<64;k++) a += Mm[n*64+k]*Tt[k*16+o];
      Y1[((size_t)b*NN+n)*32 + g*16 + o] = a;
      ps += a; pq += a*a;
    }
    red[tid]=(double)ps;
    __syncthreads();
    if (tid<16){ double t=0; for (int r=tid;r<256;r+=16) t+=red[r]; atomicAdd(&acc[ACC_Y1+g*32+tid], t); }
    __syncthreads();
    red[tid]=(double)pq;
    __syncthreads();
    if (tid<16){ double t=0; for (int r=tid;r<256;r+=16) t+=red[r]; atomicAdd(&acc[ACC_Y1+g*32+16+tid], t); }
    __syncthreads();
  }
}

// ---------------- GCN block 2 ----------------
__global__ __launch_bounds__(256) void k_gcn2(
  const float* __restrict__ Y1, const float* __restrict__ Mmat,
  const float* __restrict__ ldg, const float* __restrict__ ldbe,
  const float* __restrict__ dg, const float* __restrict__ dbe,
  const float* __restrict__ ld1W, const float* __restrict__ ld1b,
  const float* __restrict__ d1W, const float* __restrict__ d1b,
  float* __restrict__ Y2, double* __restrict__ acc)
{
  __shared__ float Yl[NN*32];
  __shared__ float T2[NN*8];
  __shared__ float Mm[2*4096];
  __shared__ float scl[32], sht[32];
  __shared__ double red[256];
  int tid=threadIdx.x, b=blockIdx.x;
  const float* ys = Y1 + (size_t)b*NN*32;
  for (int i=tid;i<NN*32;i+=256) Yl[i]=ys[i];
  for (int i=tid;i<8192;i+=256) Mm[i]=Mmat[i];
  if (tid<32){
    int g=tid>>4, o=tid&15;
    double s=acc[ACC_Y1+g*32+o], q=acc[ACC_Y1+g*32+16+o];
    double mean=s/32768.0;
    double var=q/32768.0 - mean*mean;
    float gam = g? dg[o] : ldg[o];
    float bet = g? dbe[o] : ldbe[o];
    float sc = gam * rsqrtf((float)var + 1e-5f);
    scl[tid]=sc; sht[tid]=bet - (float)mean*sc;
  }
  __syncthreads();
  for (int i=tid;i<NN*32;i+=256){ int c=i&31; Yl[i]=Yl[i]*scl[c]+sht[c]; }
  __syncthreads();
  for (int e=tid;e<NN*8;e+=256){
    int n=e>>3, c=e&7, g=c>>2, p=c&3;
    const float* w = (g? d1W : ld1W) + p*16;
    const float* yr = &Yl[n*32 + g*16];
    float a=0.f;
    #pragma unroll
    for (int o=0;o<16;o++) a += yr[o]*w[o];
    T2[e]=a;
  }
  __syncthreads();
  float ps=0.f,pq=0.f;
  for (int m=0;m<2;m++){
    int e=tid+256*m;
    int n=e>>3, c=e&7, g=c>>2;
    float a = g? d1b[c&3] : ld1b[c&3];
    const float* mr=&Mm[g*4096+n*64];
    #pragma unroll 8
    for (int k=0;k<64;k++) a += mr[k]*T2[k*8+c];
    Y2[((size_t)b*NN+n)*8 + c] = a;
    ps+=a; pq+=a*a;
  }
  red[tid]=(double)ps; __syncthreads();
  if (tid<8){ double t=0; for (int r=tid;r<256;r+=8) t+=red[r]; atomicAdd(&acc[ACC_Y2 + (tid>>2)*8 + (tid&3)], t); }
  __syncthreads();
  red[tid]=(double)pq; __syncthreads();
  if (tid<8){ double t=0; for (int r=tid;r<256;r+=8) t+=red[r]; atomicAdd(&acc[ACC_Y2 + (tid>>2)*8 + 4 + (tid&3)], t); }
}

// ---------------- BN(Y2) -> feat -> cls layer1 ----------------
__global__ __launch_bounds__(64) void k_featcls(
  const float* __restrict__ Y2,
  const float* __restrict__ ld1g, const float* __restrict__ ld1be,
  const float* __restrict__ d1g, const float* __restrict__ d1be,
  const float* __restrict__ W1, const float* __restrict__ b1,
  float* __restrict__ out1, double* __restrict__ acc)
{
  __shared__ float f[128];
  __shared__ float scl[8], sht[8];
  int tid=threadIdx.x, b=blockIdx.x;
  if (tid<8){
    int g=tid>>2, p=tid&3;
    double s=acc[ACC_Y2+g*8+p], q=acc[ACC_Y2+g*8+4+p];
    double mean=s/32768.0;
    double var=q/32768.0-mean*mean;
    float gam = g? d1g[p]:ld1g[p];
    float bet = g? d1be[p]:ld1be[p];
    float sc = gam*rsqrtf((float)var+1e-5f);
    scl[tid]=sc; sht[tid]=bet-(float)mean*sc;
  }
  __syncthreads();
  {
    const float* yr = Y2 + ((size_t)b*NN+tid)*8;
    float lf=0.f, gf=0.f;
    #pragma unroll
    for (int p=0;p<4;p++){
      lf += yr[p]*scl[p]+sht[p];
      gf += yr[4+p]*scl[4+p]+sht[4+p];
    }
    f[2*tid]   = lf*0.25f;
    f[2*tid+1] = gf*0.25f;
  }
  __syncthreads();
  if (tid<32){
    const float* w = W1 + tid*128;
    float a = b1[tid];
    #pragma unroll 4
    for (int m=0;m<128;m++) a += w[m]*f[m];
    out1[b*32+tid]=a;
    atomicAdd(&acc[ACC_O1+tid], (double)a);
    atomicAdd(&acc[ACC_O1+32+tid], (double)(a*a));
  }
}

// ---------------- BN(out1) -> cls layer2 -> log_softmax ----------------
__global__ __launch_bounds__(64) void k_cls2(
  const float* __restrict__ out1,
  const float* __restrict__ cg, const float* __restrict__ cbe,
  const float* __restrict__ W2, const float* __restrict__ b2,
  const double* __restrict__ acc, float* __restrict__ out)
{
  __shared__ float v[32];
  __shared__ float z[2];
  int tid=threadIdx.x, b=blockIdx.x;
  if (tid<32){
    double s=acc[ACC_O1+tid], q=acc[ACC_O1+32+tid];
    double mean=s/512.0;
    double var=q/512.0-mean*mean;
    float sc=cg[tid]*rsqrtf((float)var+1e-5f);
    float sh=cbe[tid]-(float)mean*sc;
    v[tid]=out1[b*32+tid]*sc+sh;
  }
  __syncthreads();
  if (tid<2){
    const float* w=W2+tid*32;
    float a=b2[tid];
    #pragma unroll
    for (int j=0;j<32;j++) a += w[j]*v[j];
    z[tid]=a;
  }
  __syncthreads();
  if (tid<2){
    float m=fmaxf(z[0],z[1]);
    float l=m+logf(expf(z[0]-m)+expf(z[1]-m));
    out[b*2+tid]=z[tid]-l;
  }
}

extern "C" void kernel_launch(void* const* d_in, const int* in_sizes, int n_in,
                              void* d_out, int out_size, void* d_ws, size_t ws_size,
                              hipStream_t stream) {
  (void)in_sizes; (void)n_in; (void)out_size; (void)ws_size;
  const float* x     = (const float*)d_in[0];
  const float* lgw   = (const float*)d_in[1];
  const float* gmask = (const float*)d_in[2];
  const float* fc1   = (const float*)d_in[3];
  const float* fc2   = (const float*)d_in[4];
  const float* saw   = (const float*)d_in[5];
  const float* tril  = (const float*)d_in[6];
  const float* ldW   = (const float*)d_in[7];
  const float* ldb   = (const float*)d_in[8];
  const float* ldg   = (const float*)d_in[9];
  const float* ldbe  = (const float*)d_in[10];
  const float* ld1W  = (const float*)d_in[11];
  const float* ld1b  = (const float*)d_in[12];
  const float* ld1g  = (const float*)d_in[13];
  const float* ld1be = (const float*)d_in[14];
  const float* dW    = (const float*)d_in[15];
  const float* db2   = (const float*)d_in[16];
  const float* dg    = (const float*)d_in[17];
  const float* dbe   = (const float*)d_in[18];
  const float* d1W   = (const float*)d_in[19];
  const float* d1b   = (const float*)d_in[20];
  const float* d1g   = (const float*)d_in[21];
  const float* d1be  = (const float*)d_in[22];
  const float* cW1   = (const float*)d_in[23];
  const float* cb1   = (const float*)d_in[24];
  const float* cgam  = (const float*)d_in[25];
  const float* cbet  = (const float*)d_in[26];
  const float* cW2   = (const float*)d_in[27];
  const float* cb2   = (const float*)d_in[28];
  const int*   edges = (const int*)d_in[29];

  char* ws = (char*)d_ws;
  float*  M     = (float*)(ws + WS_M);
  double* acc   = (double*)(ws + WS_ACC);
  float*  smean = (float*)(ws + WS_SMEAN);
  float*  smax  = (float*)(ws + WS_SMAX);
  float*  fc2T  = (float*)(ws + WS_FC2T);
  float*  Hbuf  = (float*)(ws + WS_H);
  float*  csum  = (float*)(ws + WS_CSUM);
  float*  cmax  = (float*)(ws + WS_CMAX);
  float*  catt  = (float*)(ws + WS_CATT);
  float*  Y1    = (float*)(ws + WS_Y1);
  float*  delta = (float*)(ws + WS_DELTA);
  float*  Y2    = (float*)(ws + WS_Y2);
  float*  out1  = (float*)(ws + WS_OUT1);
  float*  out   = (float*)d_out;

  k_graph<<<10, 256, 0, stream>>>(lgw, gmask, tril, edges, fc2, M, fc2T, acc);
  k_stats<<<dim3(NB, 3), 256, 0, stream>>>(x, csum, cmax);
  k_mlp1<<<dim3(NB, 2), 256, 0, stream>>>(csum, cmax, fc1, Hbuf);
  k_mlp2<<<NB, 256, 0, stream>>>(Hbuf, fc2T, catt);
  k_wav<<<dim3(NB, 16), 256, 0, stream>>>(x, catt, delta, smean, smax);
  k_gcn1<<<NB, 256, 0, stream>>>(delta, M, smean, smax, saw, ldW, ldb, dW, db2, Y1, acc);
  k_gcn2<<<NB, 256, 0, stream>>>(Y1, M, ldg, ldbe, dg, dbe, ld1W, ld1b, d1W, d1b, Y2, acc);
  k_featcls<<<NB, 64, 0, stream>>>(Y2, ld1g, ld1be, d1g, d1be, cW1, cb1, out1, acc);
  k_cls2<<<NB, 64, 0, stream>>>(out1, cgam, cbet, cW2, cb2, acc, out);
}

// Round 6
// 188.350 us; speedup vs baseline: 1.0811x; 1.0811x over previous
//
#include <hip/hip_runtime.h>
#include <math.h>

#define NB 512
#define NN 64
#define TL 657
#define LV1 328
#define LV2 164
#define LV3 82
#define LV4 41
#define HID 82
#define BAND 219   // 657/3
#define ST 66      // padded LDS stride for 64x64 matrices

// workspace byte offsets (aliased by liveness; max ~9.8 MB)
#define WS_M      0          // 2*4096 f32
#define WS_ACC    32768      // 512 doubles
#define WS_SMEAN  36864
#define WS_SMAX   167936
#define WS_FC2T   299008     // 82*657 f32 -> ends 514504 (pad 514560)
#define WS_H      514560     // 512*82 f32 -> ends 682496
#define WS_CSUM   682496     // 512*657 f32 -> ends 2028032
#define WS_CMAX   2028032    // -> ends 3373568
#define WS_CATT   3373568    // -> ends 4719104
#define WS_Y1     682496     // 512*64*32 f32 (aliases csum/cmax/catt; dead by gcn1) ends 4876800
#define WS_DELTA  4876800    // 512*64*41 f32 -> ends 10250752
#define WS_Y2     4876800    // aliases delta (dead by gcn2)
#define WS_OUT1   5925376    // 512*32 f32

// accumulator (double) indices
#define ACC_Y1 0
#define ACC_Y2 64
#define ACC_O1 80

__device__ __forceinline__ float sigmoidf_(float v){ return 1.0f/(1.0f+expf(-v)); }

__device__ __forceinline__ void wav_level(float* __restrict__ dst, const float* __restrict__ src,
                                          int outL, int inL, int lane){
  const float DLO[8] = {0.23037781330885523f, 0.7148465705525415f, 0.6308807679295904f,
                        -0.02798376941698385f, -0.18703481171888114f, 0.030841381835986965f,
                        0.032883011666982945f, -0.010597401784997278f};
  for (int k=lane; k<outL; k+=64){
    int i0 = 2*k - 3;
    float a = 0.f;
    #pragma unroll
    for (int j=0;j<8;j++){
      int idx = i0 + j;
      idx = (idx < 0) ? idx + inL : ((idx >= inL) ? idx - inL : idx);
      a += src[idx]*DLO[j];
    }
    dst[k] = a;
  }
}

// 64x64 matmul, 8 waves (512 threads), wave wv does rows [8wv,8wv+8).
// Lane owns column `lane`. acc-per-row + 16-reg B-chunks: ~50 live VGPRs, no spill.
__device__ __forceinline__ void mm8(float* __restrict__ D, int dstride,
                                    const float* __restrict__ A, const float* __restrict__ Bm){
  int tid = threadIdx.x;
  int wv = tid >> 6, lane = tid & 63;
  int i0 = wv*8;
  float acc8[8];
  #pragma unroll
  for (int i=0;i<8;i++) acc8[i]=0.f;
  #pragma unroll
  for (int kc=0; kc<4; kc++){
    float bb[16];
    #pragma unroll
    for (int j=0;j<16;j++) bb[j] = Bm[(kc*16+j)*ST + lane];
    #pragma unroll
    for (int i=0;i<8;i++){
      const float2* ar = (const float2*)&A[(i0+i)*ST + kc*16];   // (i*264 + kc*64) bytes: 8B-aligned
      float s0=0.f, s1=0.f;
      #pragma unroll
      for (int j2=0;j2<8;j2++){
        float2 v = ar[j2];
        s0 += v.x*bb[2*j2]; s1 += v.y*bb[2*j2+1];
      }
      acc8[i] += s0+s1;
    }
  }
  #pragma unroll
  for (int i=0;i<8;i++) D[(i0+i)*dstride + lane] = acc8[i];
}

// ---------------- graph prep (blocks 0,1) + tiled fc2 transpose (blocks 2..9), 512 thr ----------------
__global__ __launch_bounds__(512) void k_graph(
    const float* __restrict__ lgw, const float* __restrict__ gmask,
    const float* __restrict__ tril, const int* __restrict__ edges,
    const float* __restrict__ fc2,
    float* __restrict__ Mout, float* __restrict__ fc2T,
    double* __restrict__ acc)
{
  __shared__ float smem[3*NN*ST];      // graph: Wbuf|Amat|P1 ; transpose: 82x85 tile
  __shared__ float deg[64], hs[64], dinv[64], wself[64];
  int tid = threadIdx.x;

  if (blockIdx.x >= 2){
    // tiled transpose of fc2 (657x82) -> fc2T (82x657); 8 blocks, ~83 rows each
    int gi = blockIdx.x - 2;
    int r0 = gi*83;
    int rn = (gi==7) ? (TL - 7*83) : 83;   // 76 for last
    // load: fully coalesced linear read; LDS pad 85 breaks write conflicts
    for (int i=tid; i<rn*HID; i+=512){
      int r = i / HID, u = i - r*HID;
      smem[u*85 + r] = fc2[(size_t)r0*HID + i];
    }
    __syncthreads();
    // store: coalesced in c, conflict-free LDS reads
    for (int j=tid; j<HID*83; j+=512){
      int u = j / 83, c = j - u*83;
      if (c < rn) fc2T[u*TL + r0 + c] = smem[u*85 + c];
    }
    return;
  }

  float* Wbuf = smem;
  float* Amat = smem + NN*ST;
  float* P1   = smem + 2*NN*ST;
  int g = blockIdx.x;
  if (g==0){ for (int i=tid;i<512;i+=512) acc[i]=0.0; }
  for (int e=tid;e<4096;e+=512){
    float w;
    if (g==0) w = lgw[e];
    else {
      int i=e>>6, j=e&63;
      int aa = (i>j)? i:j, bb = (i>j)? j:i;
      w = tril[aa*(aa+1)/2 + bb] * gmask[e];
    }
    Wbuf[e] = w;
  }
  for (int i=tid;i<NN*ST;i+=512) Amat[i] = 0.f;
  if (tid<64){ deg[tid]=0.f; hs[tid]=0.f; }
  __syncthreads();
  // deg: run-length accumulation over 8 contiguous edges per thread
  {
    int e0 = tid*8;
    int runr = edges[e0];
    float runv = 0.f;
    #pragma unroll 4
    for (int i=0;i<8;i++){
      int e = e0+i;
      int r = edges[e];
      int c = edges[4096+e];
      float w = Wbuf[e];
      if (r != runr){ atomicAdd(&deg[runr], runv); runr = r; runv = 0.f; }
      runv += fabsf(w);
      if (r == c) hs[r] = 1.f;
    }
    atomicAdd(&deg[runr], runv);
  }
  __syncthreads();
  if (tid<64){
    float w_ = (hs[tid] > 0.f) ? 0.f : 1.f;
    float d = deg[tid] + w_;
    dinv[tid] = (d > 0.f) ? rsqrtf(d) : 0.f;
    wself[tid] = w_;
  }
  __syncthreads();
  for (int e=tid;e<4096;e+=512){
    int r = edges[e], c = edges[4096+e];
    float nm = dinv[r]*Wbuf[e]*dinv[c];
    atomicAdd(&Amat[c*ST+r], nm);
  }
  __syncthreads();
  if (tid<64) Amat[tid*ST+tid] += dinv[tid]*wself[tid]*dinv[tid];
  __syncthreads();
  mm8(P1,   ST, Amat, Amat); __syncthreads();   // A^2
  mm8(Wbuf, ST, P1,   P1);   __syncthreads();   // A^4 (Wbuf dead)
  mm8(&Mout[g*4096], 64, Wbuf, Amat);           // M = A^4 * A
}

// ---------------- channel stats: grid (512, 3), 16-deep load batching ----------------
__global__ __launch_bounds__(256) void k_stats(
    const float* __restrict__ x,
    float* __restrict__ csum, float* __restrict__ cmax)
{
  int tid = threadIdx.x, b = blockIdx.x, band = blockIdx.y;
  if (tid >= BAND) return;
  int col = band*BAND + tid;
  const float* p = x + (size_t)b*NN*TL + col;
  float s = 0.f, m = -INFINITY;
  for (int n=0;n<NN;n+=16){
    float v0 = p[0*TL],  v1 = p[1*TL],  v2 = p[2*TL],  v3 = p[3*TL];
    float v4 = p[4*TL],  v5 = p[5*TL],  v6 = p[6*TL],  v7 = p[7*TL];
    float v8 = p[8*TL],  v9 = p[9*TL],  vA = p[10*TL], vB = p[11*TL];
    float vC = p[12*TL], vD = p[13*TL], vE = p[14*TL], vF = p[15*TL];
    p += 16*TL;
    s += ((v0+v1)+(v2+v3)) + ((v4+v5)+(v6+v7)) + ((v8+v9)+(vA+vB)) + ((vC+vD)+(vE+vF));
    float m01 = fmaxf(fmaxf(v0,v1), fmaxf(v2,v3));
    float m23 = fmaxf(fmaxf(v4,v5), fmaxf(v6,v7));
    float m45 = fmaxf(fmaxf(v8,v9), fmaxf(vA,vB));
    float m67 = fmaxf(fmaxf(vC,vD), fmaxf(vE,vF));
    m = fmaxf(m, fmaxf(fmaxf(m01,m23), fmaxf(m45,m67)));
  }
  csum[(size_t)b*TL + col] = s;
  cmax[(size_t)b*TL + col] = m;
}

// ---------------- MLP layer 1: wave-per-output, stats in registers: grid (512,2) ----------------
__global__ __launch_bounds__(256) void k_mlp1(
    const float* __restrict__ csum, const float* __restrict__ cmax,
    const float* __restrict__ fc1, float* __restrict__ H)
{
  int tid = threadIdx.x, b = blockIdx.x, half = blockIdx.y;
  int wv = tid>>6, lane = tid&63;
  float s[11], m[11];
  #pragma unroll
  for (int i=0;i<11;i++){
    int c = lane + 64*i;
    bool ok = c < TL;
    s[i] = ok ? csum[(size_t)b*TL+c] : 0.f;
    m[i] = ok ? cmax[(size_t)b*TL+c] : 0.f;
  }
  int oend = half*41 + 41; if (oend > HID) oend = HID;
  for (int o = half*41 + wv; o < oend; o += 4){
    const float* fr = fc1 + (size_t)o*TL;
    float a = 0.f, bm = 0.f;
    #pragma unroll
    for (int i=0;i<11;i++){
      int c = lane + 64*i;
      float f = (c<TL) ? fr[c] : 0.f;
      a += f*s[i]; bm += f*m[i];
    }
    #pragma unroll
    for (int off=32;off;off>>=1){
      a  += __shfl_xor(a,off);
      bm += __shfl_xor(bm,off);
    }
    if (lane==0)
      H[(size_t)b*HID + o] = fmaxf(a*(1.0f/64.0f),0.f) + fmaxf(bm,0.f);
  }
}

// ---------------- MLP layer 2 -> catt: 3 columns/thread, coalesced fc2T: grid 512 ----------------
__global__ __launch_bounds__(256) void k_mlp2(
    const float* __restrict__ H, const float* __restrict__ fc2T,
    float* __restrict__ catt)
{
  __shared__ float h[HID];
  int tid = threadIdx.x, b = blockIdx.x;
  if (tid < HID) h[tid] = H[(size_t)b*HID + tid];
  __syncthreads();
  int c0 = tid, c1 = tid+256, c2 = tid+512;
  bool ok2 = c2 < TL;
  float a0=0.f, a1=0.f, a2=0.f;
  #pragma unroll 2
  for (int u=0;u<HID;u++){
    const float* fr = fc2T + (size_t)u*TL;
    float hv = h[u];
    a0 += fr[c0]*hv;
    a1 += fr[c1]*hv;
    if (ok2) a2 += fr[c2]*hv;
  }
  size_t base = (size_t)b*TL;
  catt[base+c0] = sigmoidf_(a0);
  catt[base+c1] = sigmoidf_(a1);
  if (ok2) catt[base+c2] = sigmoidf_(a2);
}

// ---------------- wavelet cascade + spatial stats: grid (512,16), one row per wave ----------------
__global__ __launch_bounds__(256) void k_wav(
    const float* __restrict__ x, const float* __restrict__ catt_g,
    float* __restrict__ delta, float* __restrict__ smean, float* __restrict__ smax)
{
  __shared__ float catt[TL];
  __shared__ float yb[4][TL];
  __shared__ float o1b[4][LV1];
  __shared__ float o2b[4][LV2];
  __shared__ float o3b[4][LV3];
  int tid = threadIdx.x, b = blockIdx.x;
  for (int i=tid;i<TL;i+=256) catt[i] = catt_g[(size_t)b*TL + i];
  __syncthreads();
  int wv = tid>>6, lane = tid&63;
  int n = blockIdx.y*4 + wv;
  float* y  = yb[wv];
  float* p1 = o1b[wv];
  float* p2 = o2b[wv];
  float* p3 = o3b[wv];
  const float DLO[8] = {0.23037781330885523f, 0.7148465705525415f, 0.6308807679295904f,
                        -0.02798376941698385f, -0.18703481171888114f, 0.030841381835986965f,
                        0.032883011666982945f, -0.010597401784997278f};
  const float* row = x + ((size_t)b*NN + n)*TL;
  float ls = 0.f, lm = -INFINITY;
  #pragma unroll
  for (int i=0;i<11;i++){
    int t = lane + 64*i;
    if (t < TL){
      float v = row[t]*catt[t];
      y[t] = v; ls += v; lm = fmaxf(lm,v);
    }
  }
  #pragma unroll
  for (int off=32;off;off>>=1){
    ls += __shfl_xor(ls,off);
    lm = fmaxf(lm, __shfl_xor(lm,off));
  }
  if (lane==0){ smean[b*NN+n] = ls*(1.0f/657.0f); smax[b*NN+n] = lm; }
  wav_level(p1, y,  LV1, TL,  lane);
  wav_level(p2, p1, LV2, LV1, lane);
  wav_level(p3, p2, LV3, LV2, lane);
  if (lane < LV4){
    int i0 = 2*lane - 3;
    float a = 0.f;
    #pragma unroll
    for (int j=0;j<8;j++){
      int idx = i0 + j;
      idx = (idx < 0) ? idx + LV3 : ((idx >= LV3) ? idx - LV3 : idx);
      a += p3[idx]*DLO[j];
    }
    delta[((size_t)b*NN + n)*LV4 + lane] = a;
  }
}

// ---------------- GCN block 1 (+ fused spatial attention scale) ----------------
__global__ __launch_bounds__(256) void k_gcn1(
  const float* __restrict__ delta, const float* __restrict__ Mmat,
  const float* __restrict__ smean, const float* __restrict__ smax,
  const float* __restrict__ saw,
  const float* __restrict__ ldW, const float* __restrict__ ldb,
  const float* __restrict__ dW, const float* __restrict__ db2,
  float* __restrict__ Y1, double* __restrict__ acc)
{
  __shared__ float Dl[NN*LV4];
  __shared__ float Tt[NN*16];
  __shared__ float Mm[4096];
  __shared__ float Wl[16*LV4];
  __shared__ float satt[NN];
  __shared__ double red[256];
  int tid=threadIdx.x, b=blockIdx.x;
  if (tid < NN){
    float a = 0.f;
    #pragma unroll
    for (int kw=0;kw<7;kw++){
      int w = tid + kw - 3;
      if (0<=w && w<NN) a += smean[b*NN+w]*saw[21+kw] + smax[b*NN+w]*saw[70+kw];
    }
    satt[tid] = sigmoidf_(a);
  }
  __syncthreads();
  const float* ds = delta + (size_t)b*NN*LV4;
  for (int i=tid;i<NN*LV4;i+=256) Dl[i] = ds[i]*satt[i/LV4];
  for (int g=0; g<2; g++){
    const float* Ws = g ? dW : ldW;
    const float* bs = g ? db2 : ldb;
    for (int i=tid;i<16*LV4;i+=256) Wl[i]=Ws[i];
    for (int i=tid;i<4096;i+=256) Mm[i]=Mmat[g*4096+i];
    __syncthreads();
    for (int e=tid;e<NN*16;e+=256){
      int n=e>>4, o=e&15;
      const float* dr=&Dl[n*LV4];
      const float* wr=&Wl[o*LV4];
      float a=0.f;
      #pragma unroll 8
      for (int c=0;c<LV4;c++) a += dr[c]*wr[c];
      Tt[e]=a;
    }
    __syncthreads();
    float bias = bs[tid&15];
    float ps=0.f, pq=0.f;
    for (int m=0;m<4;m++){
      int e=tid+256*m;
      int n=e>>4, o=e&15;
      float a=bias;
      #pragma unroll 8
      for (int k=0;k<64;k++) a += Mm[n*64+k]*Tt[k*16+o];
      Y1[((size_t)b*NN+n)*32 + g*16 + o] = a;
      ps += a; pq += a*a;
    }
    red[tid]=(double)ps;
    __syncthreads();
    if (tid<16){ double t=0; for (int r=tid;r<256;r+=16) t+=red[r]; atomicAdd(&acc[ACC_Y1+g*32+tid], t); }
    __syncthreads();
    red[tid]=(double)pq;
    __syncthreads();
    if (tid<16){ double t=0; for (int r=tid;r<256;r+=16) t+=red[r]; atomicAdd(&acc[ACC_Y1+g*32+16+tid], t); }
    __syncthreads();
  }
}

// ---------------- GCN block 2 ----------------
__global__ __launch_bounds__(256) void k_gcn2(
  const float* __restrict__ Y1, const float* __restrict__ Mmat,
  const float* __restrict__ ldg, const float* __restrict__ ldbe,
  const float* __restrict__ dg, const float* __restrict__ dbe,
  const float* __restrict__ ld1W, const float* __restrict__ ld1b,
  const float* __restrict__ d1W, const float* __restrict__ d1b,
  float* __restrict__ Y2, double* __restrict__ acc)
{
  __shared__ float Yl[NN*32];
  __shared__ float T2[NN*8];
  __shared__ float Mm[2*4096];
  __shared__ float scl[32], sht[32];
  __shared__ double red[256];
  int tid=threadIdx.x, b=blockIdx.x;
  const float* ys = Y1 + (size_t)b*NN*32;
  for (int i=tid;i<NN*32;i+=256) Yl[i]=ys[i];
  for (int i=tid;i<8192;i+=256) Mm[i]=Mmat[i];
  if (tid<32){
    int g=tid>>4, o=tid&15;
    double s=acc[ACC_Y1+g*32+o], q=acc[ACC_Y1+g*32+16+o];
    double mean=s/32768.0;
    double var=q/32768.0 - mean*mean;
    float gam = g? dg[o] : ldg[o];
    float bet = g? dbe[o] : ldbe[o];
    float sc = gam * rsqrtf((float)var + 1e-5f);
    scl[tid]=sc; sht[tid]=bet - (float)mean*sc;
  }
  __syncthreads();
  for (int i=tid;i<NN*32;i+=256){ int c=i&31; Yl[i]=Yl[i]*scl[c]+sht[c]; }
  __syncthreads();
  for (int e=tid;e<NN*8;e+=256){
    int n=e>>3, c=e&7, g=c>>2, p=c&3;
    const float* w = (g? d1W : ld1W) + p*16;
    const float* yr = &Yl[n*32 + g*16];
    float a=0.f;
    #pragma unroll
    for (int o=0;o<16;o++) a += yr[o]*w[o];
    T2[e]=a;
  }
  __syncthreads();
  float ps=0.f,pq=0.f;
  for (int m=0;m<2;m++){
    int e=tid+256*m;
    int n=e>>3, c=e&7, g=c>>2;
    float a = g? d1b[c&3] : ld1b[c&3];
    const float* mr=&Mm[g*4096+n*64];
    #pragma unroll 8
    for (int k=0;k<64;k++) a += mr[k]*T2[k*8+c];
    Y2[((size_t)b*NN+n)*8 + c] = a;
    ps+=a; pq+=a*a;
  }
  red[tid]=(double)ps; __syncthreads();
  if (tid<8){ double t=0; for (int r=tid;r<256;r+=8) t+=red[r]; atomicAdd(&acc[ACC_Y2 + (tid>>2)*8 + (tid&3)], t); }
  __syncthreads();
  red[tid]=(double)pq; __syncthreads();
  if (tid<8){ double t=0; for (int r=tid;r<256;r+=8) t+=red[r]; atomicAdd(&acc[ACC_Y2 + (tid>>2)*8 + 4 + (tid&3)], t); }
}

// ---------------- BN(Y2) -> feat -> cls layer1 ----------------
__global__ __launch_bounds__(64) void k_featcls(
  const float* __restrict__ Y2,
  const float* __restrict__ ld1g, const float* __restrict__ ld1be,
  const float* __restrict__ d1g, const float* __restrict__ d1be,
  const float* __restrict__ W1, const float* __restrict__ b1,
  float* __restrict__ out1, double* __restrict__ acc)
{
  __shared__ float f[128];
  __shared__ float scl[8], sht[8];
  int tid=threadIdx.x, b=blockIdx.x;
  if (tid<8){
    int g=tid>>2, p=tid&3;
    double s=acc[ACC_Y2+g*8+p], q=acc[ACC_Y2+g*8+4+p];
    double mean=s/32768.0;
    double var=q/32768.0-mean*mean;
    float gam = g? d1g[p]:ld1g[p];
    float bet = g? d1be[p]:ld1be[p];
    float sc = gam*rsqrtf((float)var+1e-5f);
    scl[tid]=sc; sht[tid]=bet-(float)mean*sc;
  }
  __syncthreads();
  {
    const float* yr = Y2 + ((size_t)b*NN+tid)*8;
    float lf=0.f, gf=0.f;
    #pragma unroll
    for (int p=0;p<4;p++){
      lf += yr[p]*scl[p]+sht[p];
      gf += yr[4+p]*scl[4+p]+sht[4+p];
    }
    f[2*tid]   = lf*0.25f;
    f[2*tid+1] = gf*0.25f;
  }
  __syncthreads();
  if (tid<32){
    const float* w = W1 + tid*128;
    float a = b1[tid];
    #pragma unroll 4
    for (int m=0;m<128;m++) a += w[m]*f[m];
    out1[b*32+tid]=a;
    atomicAdd(&acc[ACC_O1+tid], (double)a);
    atomicAdd(&acc[ACC_O1+32+tid], (double)(a*a));
  }
}

// ---------------- BN(out1) -> cls layer2 -> log_softmax ----------------
__global__ __launch_bounds__(64) void k_cls2(
  const float* __restrict__ out1,
  const float* __restrict__ cg, const float* __restrict__ cbe,
  const float* __restrict__ W2, const float* __restrict__ b2,
  const double* __restrict__ acc, float* __restrict__ out)
{
  __shared__ float v[32];
  __shared__ float z[2];
  int tid=threadIdx.x, b=blockIdx.x;
  if (tid<32){
    double s=acc[ACC_O1+tid], q=acc[ACC_O1+32+tid];
    double mean=s/512.0;
    double var=q/512.0-mean*mean;
    float sc=cg[tid]*rsqrtf((float)var+1e-5f);
    float sh=cbe[tid]-(float)mean*sc;
    v[tid]=out1[b*32+tid]*sc+sh;
  }
  __syncthreads();
  if (tid<2){
    const float* w=W2+tid*32;
    float a=b2[tid];
    #pragma unroll
    for (int j=0;j<32;j++) a += w[j]*v[j];
    z[tid]=a;
  }
  __syncthreads();
  if (tid<2){
    float m=fmaxf(z[0],z[1]);
    float l=m+logf(expf(z[0]-m)+expf(z[1]-m));
    out[b*2+tid]=z[tid]-l;
  }
}

extern "C" void kernel_launch(void* const* d_in, const int* in_sizes, int n_in,
                              void* d_out, int out_size, void* d_ws, size_t ws_size,
                              hipStream_t stream) {
  (void)in_sizes; (void)n_in; (void)out_size; (void)ws_size;
  const float* x     = (const float*)d_in[0];
  const float* lgw   = (const float*)d_in[1];
  const float* gmask = (const float*)d_in[2];
  const float* fc1   = (const float*)d_in[3];
  const float* fc2   = (const float*)d_in[4];
  const float* saw   = (const float*)d_in[5];
  const float* tril  = (const float*)d_in[6];
  const float* ldW   = (const float*)d_in[7];
  const float* ldb   = (const float*)d_in[8];
  const float* ldg   = (const float*)d_in[9];
  const float* ldbe  = (const float*)d_in[10];
  const float* ld1W  = (const float*)d_in[11];
  const float* ld1b  = (const float*)d_in[12];
  const float* ld1g  = (const float*)d_in[13];
  const float* ld1be = (const float*)d_in[14];
  const float* dW    = (const float*)d_in[15];
  const float* db2   = (const float*)d_in[16];
  const float* dg    = (const float*)d_in[17];
  const float* dbe   = (const float*)d_in[18];
  const float* d1W   = (const float*)d_in[19];
  const float* d1b   = (const float*)d_in[20];
  const float* d1g   = (const float*)d_in[21];
  const float* d1be  = (const float*)d_in[22];
  const float* cW1   = (const float*)d_in[23];
  const float* cb1   = (const float*)d_in[24];
  const float* cgam  = (const float*)d_in[25];
  const float* cbet  = (const float*)d_in[26];
  const float* cW2   = (const float*)d_in[27];
  const float* cb2   = (const float*)d_in[28];
  const int*   edges = (const int*)d_in[29];

  char* ws = (char*)d_ws;
  float*  M     = (float*)(ws + WS_M);
  double* acc   = (double*)(ws + WS_ACC);
  float*  smean = (float*)(ws + WS_SMEAN);
  float*  smax  = (float*)(ws + WS_SMAX);
  float*  fc2T  = (float*)(ws + WS_FC2T);
  float*  Hbuf  = (float*)(ws + WS_H);
  float*  csum  = (float*)(ws + WS_CSUM);
  float*  cmax  = (float*)(ws + WS_CMAX);
  float*  catt  = (float*)(ws + WS_CATT);
  float*  Y1    = (float*)(ws + WS_Y1);
  float*  delta = (float*)(ws + WS_DELTA);
  float*  Y2    = (float*)(ws + WS_Y2);
  float*  out1  = (float*)(ws + WS_OUT1);
  float*  out   = (float*)d_out;

  k_graph<<<10, 512, 0, stream>>>(lgw, gmask, tril, edges, fc2, M, fc2T, acc);
  k_stats<<<dim3(NB, 3), 256, 0, stream>>>(x, csum, cmax);
  k_mlp1<<<dim3(NB, 2), 256, 0, stream>>>(csum, cmax, fc1, Hbuf);
  k_mlp2<<<NB, 256, 0, stream>>>(Hbuf, fc2T, catt);
  k_wav<<<dim3(NB, 16), 256, 0, stream>>>(x, catt, delta, smean, smax);
  k_gcn1<<<NB, 256, 0, stream>>>(delta, M, smean, smax, saw, ldW, ldb, dW, db2, Y1, acc);
  k_gcn2<<<NB, 256, 0, stream>>>(Y1, M, ldg, ldbe, dg, dbe, ld1W, ld1b, d1W, d1b, Y2, acc);
  k_featcls<<<NB, 64, 0, stream>>>(Y2, ld1g, ld1be, d1g, d1be, cW1, cb1, out1, acc);
  k_cls2<<<NB, 64, 0, stream>>>(out1, cgam, cbet, cW2, cb2, acc, out);
}

// Round 7
// 182.967 us; speedup vs baseline: 1.1129x; 1.0294x over previous
//
#include <hip/hip_runtime.h>
#include <math.h>

#define NB 512
#define NN 64
#define TL 657
#define LV1 328
#define LV2 164
#define LV3 82
#define LV4 41
#define HID 82
#define ST 66      // padded LDS stride for 64x64 matrices

// workspace byte offsets (aliased by liveness)
#define WS_M      0          // 2*4096 f32
#define WS_ACC    32768      // 512 doubles
#define WS_SMEAN  36864
#define WS_SMAX   167936
#define WS_FC2T   299008     // 82*657 f32 -> ends 514504 (pad 514560)
#define WS_CSUM   682496     // 512*657 f32 -> ends 2028032
#define WS_CMAX   2028032    // -> ends 3373568
#define WS_CATT   3373568    // -> ends 4719104
#define WS_Y1     682496     // 512*64*32 f32 (aliases csum/cmax/catt; dead by gcn1) ends 4876800
#define WS_DELTA  4876800    // 512*64*41 f32 -> ends 10250752
#define WS_Y2     4876800    // aliases delta (dead by gcn2)
#define WS_OUT1   5925376    // 512*32 f32

// accumulator (double) indices
#define ACC_Y1 0
#define ACC_Y2 64
#define ACC_O1 80

__device__ __forceinline__ float sigmoidf_(float v){ return 1.0f/(1.0f+expf(-v)); }

__device__ __forceinline__ void wav_level(float* __restrict__ dst, const float* __restrict__ src,
                                          int outL, int inL, int lane){
  const float DLO[8] = {0.23037781330885523f, 0.7148465705525415f, 0.6308807679295904f,
                        -0.02798376941698385f, -0.18703481171888114f, 0.030841381835986965f,
                        0.032883011666982945f, -0.010597401784997278f};
  for (int k=lane; k<outL; k+=64){
    int i0 = 2*k - 3;
    float a = 0.f;
    #pragma unroll
    for (int j=0;j<8;j++){
      int idx = i0 + j;
      idx = (idx < 0) ? idx + inL : ((idx >= inL) ? idx - inL : idx);
      a += src[idx]*DLO[j];
    }
    dst[k] = a;
  }
}

// 64x64 matmul, 8 waves (512 threads), wave wv does rows [8wv,8wv+8).
__device__ __forceinline__ void mm8(float* __restrict__ D, int dstride,
                                    const float* __restrict__ A, const float* __restrict__ Bm){
  int tid = threadIdx.x;
  int wv = tid >> 6, lane = tid & 63;
  int i0 = wv*8;
  float acc8[8];
  #pragma unroll
  for (int i=0;i<8;i++) acc8[i]=0.f;
  #pragma unroll
  for (int kc=0; kc<4; kc++){
    float bb[16];
    #pragma unroll
    for (int j=0;j<16;j++) bb[j] = Bm[(kc*16+j)*ST + lane];
    #pragma unroll
    for (int i=0;i<8;i++){
      const float2* ar = (const float2*)&A[(i0+i)*ST + kc*16];
      float s0=0.f, s1=0.f;
      #pragma unroll
      for (int j2=0;j2<8;j2++){
        float2 v = ar[j2];
        s0 += v.x*bb[2*j2]; s1 += v.y*bb[2*j2+1];
      }
      acc8[i] += s0+s1;
    }
  }
  #pragma unroll
  for (int i=0;i<8;i++) D[(i0+i)*dstride + lane] = acc8[i];
}

// ---------------- fused front: channel stats (blocks 0..1023) + graph prep (1024,1025)
// ----------------                + fc2 transpose (1026..1033). 512 threads.
__global__ __launch_bounds__(512) void k_front(
    const float* __restrict__ x,
    const float* __restrict__ lgw, const float* __restrict__ gmask,
    const float* __restrict__ tril, const int* __restrict__ edges,
    const float* __restrict__ fc2,
    float* __restrict__ csum, float* __restrict__ cmax,
    float* __restrict__ Mout, float* __restrict__ fc2T,
    double* __restrict__ acc)
{
  __shared__ float smem[3*NN*ST];
  __shared__ float deg[64], hs[64], dinv[64], wself[64];
  int tid = threadIdx.x;
  int bid = blockIdx.x;

  if (bid < 2*NB){
    // ---- channel stats: band 0 = cols [0,329), band 1 = [329,657) ----
    int b = bid >> 1, band = bid & 1;
    int c0   = band ? 329 : 0;
    int len  = band ? 328 : 329;
    if (tid >= len) return;
    int col = c0 + tid;
    const float* p = x + (size_t)b*NN*TL + col;
    float s = 0.f, m = -INFINITY;
    for (int n=0;n<NN;n+=16){
      float v0 = p[0*TL],  v1 = p[1*TL],  v2 = p[2*TL],  v3 = p[3*TL];
      float v4 = p[4*TL],  v5 = p[5*TL],  v6 = p[6*TL],  v7 = p[7*TL];
      float v8 = p[8*TL],  v9 = p[9*TL],  vA = p[10*TL], vB = p[11*TL];
      float vC = p[12*TL], vD = p[13*TL], vE = p[14*TL], vF = p[15*TL];
      p += 16*TL;
      s += ((v0+v1)+(v2+v3)) + ((v4+v5)+(v6+v7)) + ((v8+v9)+(vA+vB)) + ((vC+vD)+(vE+vF));
      float m01 = fmaxf(fmaxf(v0,v1), fmaxf(v2,v3));
      float m23 = fmaxf(fmaxf(v4,v5), fmaxf(v6,v7));
      float m45 = fmaxf(fmaxf(v8,v9), fmaxf(vA,vB));
      float m67 = fmaxf(fmaxf(vC,vD), fmaxf(vE,vF));
      m = fmaxf(m, fmaxf(fmaxf(m01,m23), fmaxf(m45,m67)));
    }
    csum[(size_t)b*TL + col] = s;
    cmax[(size_t)b*TL + col] = m;
    return;
  }

  int gi = bid - 2*NB;    // 0..9
  if (gi >= 2){
    // ---- tiled transpose of fc2 (657x82) -> fc2T (82x657) ----
    int t8 = gi - 2;      // 0..7
    int r0 = t8*83;
    int rn = (t8==7) ? (TL - 7*83) : 83;
    for (int i=tid; i<rn*HID; i+=512){
      int r = i / HID, u = i - r*HID;
      smem[u*85 + r] = fc2[(size_t)r0*HID + i];
    }
    __syncthreads();
    for (int j=tid; j<HID*83; j+=512){
      int u = j / 83, c = j - u*83;
      if (c < rn) fc2T[u*TL + r0 + c] = smem[u*85 + c];
    }
    return;
  }

  // ---- graph prep: g=0 local, g=1 global ----
  float* Wbuf = smem;
  float* Amat = smem + NN*ST;
  float* P1   = smem + 2*NN*ST;
  int g = gi;
  if (g==0 && tid<512) acc[tid]=0.0;
  for (int e=tid;e<4096;e+=512){
    float w;
    if (g==0) w = lgw[e];
    else {
      int i=e>>6, j=e&63;
      int aa = (i>j)? i:j, bb = (i>j)? j:i;
      w = tril[aa*(aa+1)/2 + bb] * gmask[e];
    }
    Wbuf[e] = w;
  }
  for (int i=tid;i<NN*ST;i+=512) Amat[i] = 0.f;
  if (tid<64){ deg[tid]=0.f; hs[tid]=0.f; }
  __syncthreads();
  {
    int e0 = tid*8;
    int runr = edges[e0];
    float runv = 0.f;
    #pragma unroll 4
    for (int i=0;i<8;i++){
      int e = e0+i;
      int r = edges[e];
      int c = edges[4096+e];
      float w = Wbuf[e];
      if (r != runr){ atomicAdd(&deg[runr], runv); runr = r; runv = 0.f; }
      runv += fabsf(w);
      if (r == c) hs[r] = 1.f;
    }
    atomicAdd(&deg[runr], runv);
  }
  __syncthreads();
  if (tid<64){
    float w_ = (hs[tid] > 0.f) ? 0.f : 1.f;
    float d = deg[tid] + w_;
    dinv[tid] = (d > 0.f) ? rsqrtf(d) : 0.f;
    wself[tid] = w_;
  }
  __syncthreads();
  for (int e=tid;e<4096;e+=512){
    int r = edges[e], c = edges[4096+e];
    float nm = dinv[r]*Wbuf[e]*dinv[c];
    atomicAdd(&Amat[c*ST+r], nm);
  }
  __syncthreads();
  if (tid<64) Amat[tid*ST+tid] += dinv[tid]*wself[tid]*dinv[tid];
  __syncthreads();
  mm8(P1,   ST, Amat, Amat); __syncthreads();   // A^2
  mm8(Wbuf, ST, P1,   P1);   __syncthreads();   // A^4
  mm8(&Mout[g*4096], 64, Wbuf, Amat);           // A^5
}

// ---------------- fused MLP (both layers) -> catt: grid 512, 512 threads ----------------
__global__ __launch_bounds__(512) void k_mlp(
    const float* __restrict__ csum, const float* __restrict__ cmax,
    const float* __restrict__ fc1, const float* __restrict__ fc2T,
    float* __restrict__ catt)
{
  __shared__ float cs[TL], cm[TL];
  __shared__ float h[HID];
  int tid = threadIdx.x, b = blockIdx.x;
  for (int i=tid;i<TL;i+=512){
    cs[i] = csum[(size_t)b*TL + i];
    cm[i] = cmax[(size_t)b*TL + i];
  }
  __syncthreads();
  int wv = tid>>6, lane = tid&63;
  for (int o=wv; o<HID; o+=8){
    const float* fr = fc1 + (size_t)o*TL;
    float a = 0.f, bm = 0.f;
    #pragma unroll
    for (int i=0;i<11;i++){
      int c = lane + 64*i;
      if (c < TL){
        float f = fr[c];
        a += f*cs[c]; bm += f*cm[c];
      }
    }
    #pragma unroll
    for (int off=32;off;off>>=1){
      a  += __shfl_xor(a,off);
      bm += __shfl_xor(bm,off);
    }
    if (lane==0)
      h[o] = fmaxf(a*(1.0f/64.0f),0.f) + fmaxf(bm,0.f);
  }
  __syncthreads();
  for (int c=tid;c<TL;c+=512){
    float a=0.f;
    #pragma unroll 4
    for (int u=0;u<HID;u++) a += fc2T[(size_t)u*TL + c]*h[u];
    catt[(size_t)b*TL + c] = sigmoidf_(a);
  }
}

// ---------------- wavelet cascade + spatial stats: grid (512,16), one row per wave ----------------
__global__ __launch_bounds__(256) void k_wav(
    const float* __restrict__ x, const float* __restrict__ catt_g,
    float* __restrict__ delta, float* __restrict__ smean, float* __restrict__ smax)
{
  __shared__ float catt[TL];
  __shared__ float yb[4][TL];
  __shared__ float o1b[4][LV1];
  __shared__ float o2b[4][LV2];
  __shared__ float o3b[4][LV3];
  int tid = threadIdx.x, b = blockIdx.x;
  for (int i=tid;i<TL;i+=256) catt[i] = catt_g[(size_t)b*TL + i];
  __syncthreads();
  int wv = tid>>6, lane = tid&63;
  int n = blockIdx.y*4 + wv;
  float* y  = yb[wv];
  float* p1 = o1b[wv];
  float* p2 = o2b[wv];
  float* p3 = o3b[wv];
  const float DLO[8] = {0.23037781330885523f, 0.7148465705525415f, 0.6308807679295904f,
                        -0.02798376941698385f, -0.18703481171888114f, 0.030841381835986965f,
                        0.032883011666982945f, -0.010597401784997278f};
  const float* row = x + ((size_t)b*NN + n)*TL;
  float ls = 0.f, lm = -INFINITY;
  #pragma unroll
  for (int i=0;i<11;i++){
    int t = lane + 64*i;
    if (t < TL){
      float v = row[t]*catt[t];
      y[t] = v; ls += v; lm = fmaxf(lm,v);
    }
  }
  #pragma unroll
  for (int off=32;off;off>>=1){
    ls += __shfl_xor(ls,off);
    lm = fmaxf(lm, __shfl_xor(lm,off));
  }
  if (lane==0){ smean[b*NN+n] = ls*(1.0f/657.0f); smax[b*NN+n] = lm; }
  wav_level(p1, y,  LV1, TL,  lane);
  wav_level(p2, p1, LV2, LV1, lane);
  wav_level(p3, p2, LV3, LV2, lane);
  if (lane < LV4){
    int i0 = 2*lane - 3;
    float a = 0.f;
    #pragma unroll
    for (int j=0;j<8;j++){
      int idx = i0 + j;
      idx = (idx < 0) ? idx + LV3 : ((idx >= LV3) ? idx - LV3 : idx);
      a += p3[idx]*DLO[j];
    }
    delta[((size_t)b*NN + n)*LV4 + lane] = a;
  }
}

// ---------------- GCN block 1 (+ fused spatial attention scale) ----------------
__global__ __launch_bounds__(256) void k_gcn1(
  const float* __restrict__ delta, const float* __restrict__ Mmat,
  const float* __restrict__ smean, const float* __restrict__ smax,
  const float* __restrict__ saw,
  const float* __restrict__ ldW, const float* __restrict__ ldb,
  const float* __restrict__ dW, const float* __restrict__ db2,
  float* __restrict__ Y1, double* __restrict__ acc)
{
  __shared__ float Dl[NN*LV4];
  __shared__ float Tt[NN*16];
  __shared__ float Mm[4096];
  __shared__ float Wl[16*LV4];
  __shared__ float satt[NN];
  __shared__ double red[256];
  int tid=threadIdx.x, b=blockIdx.x;
  if (tid < NN){
    float a = 0.f;
    #pragma unroll
    for (int kw=0;kw<7;kw++){
      int w = tid + kw - 3;
      if (0<=w && w<NN) a += smean[b*NN+w]*saw[21+kw] + smax[b*NN+w]*saw[70+kw];
    }
    satt[tid] = sigmoidf_(a);
  }
  __syncthreads();
  const float* ds = delta + (size_t)b*NN*LV4;
  for (int i=tid;i<NN*LV4;i+=256) Dl[i] = ds[i]*satt[i/LV4];
  for (int g=0; g<2; g++){
    const float* Ws = g ? dW : ldW;
    const float* bs = g ? db2 : ldb;
    for (int i=tid;i<16*LV4;i+=256) Wl[i]=Ws[i];
    for (int i=tid;i<4096;i+=256) Mm[i]=Mmat[g*4096+i];
    __syncthreads();
    for (int e=tid;e<NN*16;e+=256){
      int n=e>>4, o=e&15;
      const float* dr=&Dl[n*LV4];
      const float* wr=&Wl[o*LV4];
      float a=0.f;
      #pragma unroll 8
      for (int c=0;c<LV4;c++) a += dr[c]*wr[c];
      Tt[e]=a;
    }
    __syncthreads();
    float bias = bs[tid&15];
    float ps=0.f, pq=0.f;
    for (int m=0;m<4;m++){
      int e=tid+256*m;
      int n=e>>4, o=e&15;
      float a=bias;
      #pragma unroll 8
      for (int k=0;k<64;k++) a += Mm[n*64+k]*Tt[k*16+o];
      Y1[((size_t)b*NN+n)*32 + g*16 + o] = a;
      ps += a; pq += a*a;
    }
    red[tid]=(double)ps;
    __syncthreads();
    if (tid<16){ double t=0; for (int r=tid;r<256;r+=16) t+=red[r]; atomicAdd(&acc[ACC_Y1+g*32+tid], t); }
    __syncthreads();
    red[tid]=(double)pq;
    __syncthreads();
    if (tid<16){ double t=0; for (int r=tid;r<256;r+=16) t+=red[r]; atomicAdd(&acc[ACC_Y1+g*32+16+tid], t); }
    __syncthreads();
  }
}

// ---------------- GCN block 2 ----------------
__global__ __launch_bounds__(256) void k_gcn2(
  const float* __restrict__ Y1, const float* __restrict__ Mmat,
  const float* __restrict__ ldg, const float* __restrict__ ldbe,
  const float* __restrict__ dg, const float* __restrict__ dbe,
  const float* __restrict__ ld1W, const float* __restrict__ ld1b,
  const float* __restrict__ d1W, const float* __restrict__ d1b,
  float* __restrict__ Y2, double* __restrict__ acc)
{
  __shared__ float Yl[NN*32];
  __shared__ float T2[NN*8];
  __shared__ float Mm[2*4096];
  __shared__ float scl[32], sht[32];
  __shared__ double red[256];
  int tid=threadIdx.x, b=blockIdx.x;
  const float* ys = Y1 + (size_t)b*NN*32;
  for (int i=tid;i<NN*32;i+=256) Yl[i]=ys[i];
  for (int i=tid;i<8192;i+=256) Mm[i]=Mmat[i];
  if (tid<32){
    int g=tid>>4, o=tid&15;
    double s=acc[ACC_Y1+g*32+o], q=acc[ACC_Y1+g*32+16+o];
    double mean=s/32768.0;
    double var=q/32768.0 - mean*mean;
    float gam = g? dg[o] : ldg[o];
    float bet = g? dbe[o] : ldbe[o];
    float sc = gam * rsqrtf((float)var + 1e-5f);
    scl[tid]=sc; sht[tid]=bet - (float)mean*sc;
  }
  __syncthreads();
  for (int i=tid;i<NN*32;i+=256){ int c=i&31; Yl[i]=Yl[i]*scl[c]+sht[c]; }
  __syncthreads();
  for (int e=tid;e<NN*8;e+=256){
    int n=e>>3, c=e&7, g=c>>2, p=c&3;
    const float* w = (g? d1W : ld1W) + p*16;
    const float* yr = &Yl[n*32 + g*16];
    float a=0.f;
    #pragma unroll
    for (int o=0;o<16;o++) a += yr[o]*w[o];
    T2[e]=a;
  }
  __syncthreads();
  float ps=0.f,pq=0.f;
  for (int m=0;m<2;m++){
    int e=tid+256*m;
    int n=e>>3, c=e&7, g=c>>2;
    float a = g? d1b[c&3] : ld1b[c&3];
    const float* mr=&Mm[g*4096+n*64];
    #pragma unroll 8
    for (int k=0;k<64;k++) a += mr[k]*T2[k*8+c];
    Y2[((size_t)b*NN+n)*8 + c] = a;
    ps+=a; pq+=a*a;
  }
  red[tid]=(double)ps; __syncthreads();
  if (tid<8){ double t=0; for (int r=tid;r<256;r+=8) t+=red[r]; atomicAdd(&acc[ACC_Y2 + (tid>>2)*8 + (tid&3)], t); }
  __syncthreads();
  red[tid]=(double)pq; __syncthreads();
  if (tid<8){ double t=0; for (int r=tid;r<256;r+=8) t+=red[r]; atomicAdd(&acc[ACC_Y2 + (tid>>2)*8 + 4 + (tid&3)], t); }
}

// ---------------- BN(Y2) -> feat -> cls layer1 ----------------
__global__ __launch_bounds__(64) void k_featcls(
  const float* __restrict__ Y2,
  const float* __restrict__ ld1g, const float* __restrict__ ld1be,
  const float* __restrict__ d1g, const float* __restrict__ d1be,
  const float* __restrict__ W1, const float* __restrict__ b1,
  float* __restrict__ out1, double* __restrict__ acc)
{
  __shared__ float f[128];
  __shared__ float scl[8], sht[8];
  int tid=threadIdx.x, b=blockIdx.x;
  if (tid<8){
    int g=tid>>2, p=tid&3;
    double s=acc[ACC_Y2+g*8+p], q=acc[ACC_Y2+g*8+4+p];
    double mean=s/32768.0;
    double var=q/32768.0-mean*mean;
    float gam = g? d1g[p]:ld1g[p];
    float bet = g? d1be[p]:ld1be[p];
    float sc = gam*rsqrtf((float)var+1e-5f);
    scl[tid]=sc; sht[tid]=bet-(float)mean*sc;
  }
  __syncthreads();
  {
    const float* yr = Y2 + ((size_t)b*NN+tid)*8;
    float lf=0.f, gf=0.f;
    #pragma unroll
    for (int p=0;p<4;p++){
      lf += yr[p]*scl[p]+sht[p];
      gf += yr[4+p]*scl[4+p]+sht[4+p];
    }
    f[2*tid]   = lf*0.25f;
    f[2*tid+1] = gf*0.25f;
  }
  __syncthreads();
  if (tid<32){
    const float* w = W1 + tid*128;
    float a = b1[tid];
    #pragma unroll 4
    for (int m=0;m<128;m++) a += w[m]*f[m];
    out1[b*32+tid]=a;
    atomicAdd(&acc[ACC_O1+tid], (double)a);
    atomicAdd(&acc[ACC_O1+32+tid], (double)(a*a));
  }
}

// ---------------- BN(out1) -> cls layer2 -> log_softmax ----------------
__global__ __launch_bounds__(64) void k_cls2(
  const float* __restrict__ out1,
  const float* __restrict__ cg, const float* __restrict__ cbe,
  const float* __restrict__ W2, const float* __restrict__ b2,
  const double* __restrict__ acc, float* __restrict__ out)
{
  __shared__ float v[32];
  __shared__ float z[2];
  int tid=threadIdx.x, b=blockIdx.x;
  if (tid<32){
    double s=acc[ACC_O1+tid], q=acc[ACC_O1+32+tid];
    double mean=s/512.0;
    double var=q/512.0-mean*mean;
    float sc=cg[tid]*rsqrtf((float)var+1e-5f);
    float sh=cbe[tid]-(float)mean*sc;
    v[tid]=out1[b*32+tid]*sc+sh;
  }
  __syncthreads();
  if (tid<2){
    const float* w=W2+tid*32;
    float a=b2[tid];
    #pragma unroll
    for (int j=0;j<32;j++) a += w[j]*v[j];
    z[tid]=a;
  }
  __syncthreads();
  if (tid<2){
    float m=fmaxf(z[0],z[1]);
    float l=m+logf(expf(z[0]-m)+expf(z[1]-m));
    out[b*2+tid]=z[tid]-l;
  }
}

extern "C" void kernel_launch(void* const* d_in, const int* in_sizes, int n_in,
                              void* d_out, int out_size, void* d_ws, size_t ws_size,
                              hipStream_t stream) {
  (void)in_sizes; (void)n_in; (void)out_size; (void)ws_size;
  const float* x     = (const float*)d_in[0];
  const float* lgw   = (const float*)d_in[1];
  const float* gmask = (const float*)d_in[2];
  const float* fc1   = (const float*)d_in[3];
  const float* fc2   = (const float*)d_in[4];
  const float* saw   = (const float*)d_in[5];
  const float* tril  = (const float*)d_in[6];
  const float* ldW   = (const float*)d_in[7];
  const float* ldb   = (const float*)d_in[8];
  const float* ldg   = (const float*)d_in[9];
  const float* ldbe  = (const float*)d_in[10];
  const float* ld1W  = (const float*)d_in[11];
  const float* ld1b  = (const float*)d_in[12];
  const float* ld1g  = (const float*)d_in[13];
  const float* ld1be = (const float*)d_in[14];
  const float* dW    = (const float*)d_in[15];
  const float* db2   = (const float*)d_in[16];
  const float* dg    = (const float*)d_in[17];
  const float* dbe   = (const float*)d_in[18];
  const float* d1W   = (const float*)d_in[19];
  const float* d1b   = (const float*)d_in[20];
  const float* d1g   = (const float*)d_in[21];
  const float* d1be  = (const float*)d_in[22];
  const float* cW1   = (const float*)d_in[23];
  const float* cb1   = (const float*)d_in[24];
  const float* cgam  = (const float*)d_in[25];
  const float* cbet  = (const float*)d_in[26];
  const float* cW2   = (const float*)d_in[27];
  const float* cb2   = (const float*)d_in[28];
  const int*   edges = (const int*)d_in[29];

  char* ws = (char*)d_ws;
  float*  M     = (float*)(ws + WS_M);
  double* acc   = (double*)(ws + WS_ACC);
  float*  smean = (float*)(ws + WS_SMEAN);
  float*  smax  = (float*)(ws + WS_SMAX);
  float*  fc2T  = (float*)(ws + WS_FC2T);
  float*  csum  = (float*)(ws + WS_CSUM);
  float*  cmax  = (float*)(ws + WS_CMAX);
  float*  catt  = (float*)(ws + WS_CATT);
  float*  Y1    = (float*)(ws + WS_Y1);
  float*  delta = (float*)(ws + WS_DELTA);
  float*  Y2    = (float*)(ws + WS_Y2);
  float*  out1  = (float*)(ws + WS_OUT1);
  float*  out   = (float*)d_out;

  k_front<<<2*NB + 10, 512, 0, stream>>>(x, lgw, gmask, tril, edges, fc2,
                                         csum, cmax, M, fc2T, acc);
  k_mlp<<<NB, 512, 0, stream>>>(csum, cmax, fc1, fc2T, catt);
  k_wav<<<dim3(NB, 16), 256, 0, stream>>>(x, catt, delta, smean, smax);
  k_gcn1<<<NB, 256, 0, stream>>>(delta, M, smean, smax, saw, ldW, ldb, dW, db2, Y1, acc);
  k_gcn2<<<NB, 256, 0, stream>>>(Y1, M, ldg, ldbe, dg, dbe, ld1W, ld1b, d1W, d1b, Y2, acc);
  k_featcls<<<NB, 64, 0, stream>>>(Y2, ld1g, ld1be, d1g, d1be, cW1, cb1, out1, acc);
  k_cls2<<<NB, 64, 0, stream>>>(out1, cgam, cbet, cW2, cb2, acc, out);
}